// Round 1
// baseline (952.232 us; speedup 1.0000x reference)
//
#include <hip/hip_runtime.h>

#define TPB 256

static __device__ __forceinline__ float relu(float v) { return v > 0.f ? v : 0.f; }

// Transpose the four 128x128 weight matrices: wt[m][d*128+h] = W[m][h*128+d]
__global__ __launch_bounds__(256) void k_transpose(
    const float* __restrict__ w1l, const float* __restrict__ w1r,
    const float* __restrict__ w2l, const float* __restrict__ w2r,
    float* __restrict__ wt) {
  int i = blockIdx.x * 256 + threadIdx.x;  // 0..65535
  int m = i >> 14;
  int k = i & 16383;
  int h = k >> 7;
  int d = k & 127;
  const float* s = (m == 0) ? w1l : (m == 1) ? w1r : (m == 2) ? w2l : w2r;
  wt[(m << 14) + d * 128 + h] = s[k];
}

__global__ __launch_bounds__(256) void k_degree(const int* __restrict__ dst,
                                                int* __restrict__ deg, int e) {
  int i = blockIdx.x * 256 + threadIdx.x;
  if (i < e) atomicAdd(&deg[dst[i]], 1);
}

// Exclusive offsets via wave scan + one atomic per wave (bucket order is irrelevant).
__global__ __launch_bounds__(256) void k_scan(const int* __restrict__ deg,
                                              int* __restrict__ start,
                                              int* __restrict__ cursor,
                                              int* __restrict__ total, int n) {
  int gid = blockIdx.x * 256 + threadIdx.x;
  int lane = threadIdx.x & 63;
  int d = (gid < n) ? deg[gid] : 0;
  int incl = d;
#pragma unroll
  for (int off = 1; off < 64; off <<= 1) {
    int t = __shfl_up(incl, off, 64);
    if (lane >= off) incl += t;
  }
  int wsum = __shfl(incl, 63, 64);
  int base = 0;
  if (lane == 63) base = atomicAdd(total, wsum);
  base = __shfl(base, 63, 64);
  if (gid < n) {
    int st = base + incl - d;
    start[gid] = st;
    cursor[gid] = st;
  }
}

__global__ __launch_bounds__(256) void k_bucket(const int* __restrict__ src,
                                                const int* __restrict__ dst,
                                                int* __restrict__ cursor,
                                                int* __restrict__ bucket, int e) {
  int i = blockIdx.x * 256 + threadIdx.x;
  if (i < e) {
    int pos = atomicAdd(&cursor[dst[i]], 1);
    bucket[pos] = src[i];
  }
}

// One wave per node: mean of source rows (float2 per lane = 128 cols).
__global__ __launch_bounds__(256) void k_aggregate(const float* __restrict__ h,
                                                   const int* __restrict__ bucket,
                                                   const int* __restrict__ start,
                                                   const int* __restrict__ deg,
                                                   float* __restrict__ mean, int n) {
  int node = blockIdx.x * 4 + (threadIdx.x >> 6);
  if (node >= n) return;
  int lane = threadIdx.x & 63;
  int s = start[node];
  int cnt = deg[node];
  float ax = 0.f, ay = 0.f;
  const float* hp = h + (size_t)lane * 2;
  for (int k = s; k < s + cnt; ++k) {
    int sn = bucket[k];
    float2 v = *(const float2*)(hp + (size_t)sn * 128);
    ax += v.x;
    ay += v.y;
  }
  float inv = 1.f / (float)(cnt > 0 ? cnt : 1);
  float2 o;
  o.x = ax * inv;
  o.y = ay * inv;
  *(float2*)(mean + (size_t)node * 128 + lane * 2) = o;
}

// out[n][h] = relu( sum_d A[n][d]*Wl[h][d] + bias[h] + sum_d B[n][d]*Wr[h][d] )
// Wlt/Wrt are pre-transposed to [d][h]. MODE 0: write x1out [n,128].
// MODE 1: write interleaved out[n][h][2] = {B value (=x1), result (=x2)}.
template <int MODE>
__global__ __launch_bounds__(256) void sage_gemm(
    const float* __restrict__ A, const float* __restrict__ B,
    const float* __restrict__ Wlt, const float* __restrict__ Wrt,
    const float* __restrict__ bias, float* __restrict__ x1out,
    float* __restrict__ out, int n, int rpb) {
  __shared__ float wl[128 * 128];
  __shared__ float wr[128 * 128];
  __shared__ float bs[128];
  __shared__ float rA[16][128];
  __shared__ float rB[16][128];

  int tid = threadIdx.x;
  for (int i = tid; i < 4096; i += 256) {
    ((float4*)wl)[i] = ((const float4*)Wlt)[i];
    ((float4*)wr)[i] = ((const float4*)Wrt)[i];
  }
  if (tid < 128) bs[tid] = bias[tid];

  int rowStart = blockIdx.x * rpb;
  int rowEnd = min(rowStart + rpb, n);
  int cg = tid >> 5;          // 0..7 -> row pair
  int h4 = (tid & 31) << 2;   // output column group of 4
  __syncthreads();
  float4 bias4 = *(float4*)&bs[h4];

  for (int r0 = rowStart; r0 < rowEnd; r0 += 16) {
    int nr = min(16, rowEnd - r0);
    __syncthreads();
    for (int i = tid; i < nr * 32; i += 256) {
      int rr = i >> 5;
      int c = i & 31;
      *((float4*)&rA[rr][c * 4]) =
          *((const float4*)&A[((size_t)(r0 + rr)) * 128 + c * 4]);
      *((float4*)&rB[rr][c * 4]) =
          *((const float4*)&B[((size_t)(r0 + rr)) * 128 + c * 4]);
    }
    __syncthreads();
    int rr0 = cg * 2, rr1 = rr0 + 1;
    float4 acc0 = bias4, acc1 = bias4;
    for (int d0 = 0; d0 < 128; d0 += 4) {
      float4 a0 = *(float4*)&rA[rr0][d0];
      float4 b0 = *(float4*)&rB[rr0][d0];
      float4 a1 = *(float4*)&rA[rr1][d0];
      float4 b1 = *(float4*)&rB[rr1][d0];
      const float* a0p = &a0.x;
      const float* b0p = &b0.x;
      const float* a1p = &a1.x;
      const float* b1p = &b1.x;
#pragma unroll
      for (int j = 0; j < 4; ++j) {
        float4 wlv = *(float4*)&wl[(d0 + j) * 128 + h4];
        float4 wrv = *(float4*)&wr[(d0 + j) * 128 + h4];
        acc0.x += a0p[j] * wlv.x + b0p[j] * wrv.x;
        acc0.y += a0p[j] * wlv.y + b0p[j] * wrv.y;
        acc0.z += a0p[j] * wlv.z + b0p[j] * wrv.z;
        acc0.w += a0p[j] * wlv.w + b0p[j] * wrv.w;
        acc1.x += a1p[j] * wlv.x + b1p[j] * wrv.x;
        acc1.y += a1p[j] * wlv.y + b1p[j] * wrv.y;
        acc1.z += a1p[j] * wlv.z + b1p[j] * wrv.z;
        acc1.w += a1p[j] * wlv.w + b1p[j] * wrv.w;
      }
    }
    if (MODE == 0) {
      if (rr0 < nr) {
        float4 o = {relu(acc0.x), relu(acc0.y), relu(acc0.z), relu(acc0.w)};
        *(float4*)&x1out[((size_t)(r0 + rr0)) * 128 + h4] = o;
      }
      if (rr1 < nr) {
        float4 o = {relu(acc1.x), relu(acc1.y), relu(acc1.z), relu(acc1.w)};
        *(float4*)&x1out[((size_t)(r0 + rr1)) * 128 + h4] = o;
      }
    } else {
      if (rr0 < nr) {
        size_t base = ((size_t)(r0 + rr0) * 128 + h4) * 2;
        float4 oA = {rB[rr0][h4 + 0], relu(acc0.x), rB[rr0][h4 + 1], relu(acc0.y)};
        float4 oB = {rB[rr0][h4 + 2], relu(acc0.z), rB[rr0][h4 + 3], relu(acc0.w)};
        *(float4*)&out[base] = oA;
        *(float4*)&out[base + 4] = oB;
      }
      if (rr1 < nr) {
        size_t base = ((size_t)(r0 + rr1) * 128 + h4) * 2;
        float4 oA = {rB[rr1][h4 + 0], relu(acc1.x), rB[rr1][h4 + 1], relu(acc1.y)};
        float4 oB = {rB[rr1][h4 + 2], relu(acc1.z), rB[rr1][h4 + 3], relu(acc1.w)};
        *(float4*)&out[base] = oA;
        *(float4*)&out[base + 4] = oB;
      }
    }
  }
}

extern "C" void kernel_launch(void* const* d_in, const int* in_sizes, int n_in,
                              void* d_out, int out_size, void* d_ws, size_t ws_size,
                              hipStream_t stream) {
  const float* x = (const float*)d_in[0];
  const int* ei = (const int*)d_in[1];
  const float* w1l = (const float*)d_in[2];
  const float* b1 = (const float*)d_in[3];
  const float* w1r = (const float*)d_in[4];
  const float* w2l = (const float*)d_in[5];
  const float* b2 = (const float*)d_in[6];
  const float* w2r = (const float*)d_in[7];
  float* out = (float*)d_out;

  int n = in_sizes[0] / 128;
  int e = in_sizes[1] / 2;
  const int* src = ei;
  const int* dst = ei + e;

  char* ws = (char*)d_ws;
  size_t off = 0;
  auto alloc = [&](size_t bytes) {
    void* p = ws + off;
    off += (bytes + 255) & ~(size_t)255;
    return p;
  };
  float* wt = (float*)alloc(4 * 16384 * sizeof(float));
  int* deg = (int*)alloc((size_t)n * 4);
  int* start = (int*)alloc((size_t)n * 4);
  int* cursor = (int*)alloc((size_t)n * 4);
  int* total = (int*)alloc(256);
  int* bucket = (int*)alloc((size_t)e * 4);
  float* mean = (float*)alloc((size_t)n * 128 * sizeof(float));
  float* x1 = (float*)alloc((size_t)n * 128 * sizeof(float));
  (void)ws_size;
  (void)n_in;
  (void)out_size;

  hipMemsetAsync(deg, 0, (size_t)n * 4, stream);
  hipMemsetAsync(total, 0, 4, stream);

  k_transpose<<<256, 256, 0, stream>>>(w1l, w1r, w2l, w2r, wt);
  int gE = (e + 255) / 256;
  k_degree<<<gE, 256, 0, stream>>>(dst, deg, e);
  int gN = (n + 255) / 256;
  k_scan<<<gN, 256, 0, stream>>>(deg, start, cursor, total, n);
  k_bucket<<<gE, 256, 0, stream>>>(src, dst, cursor, bucket, e);

  int gAgg = (n + 3) / 4;
  k_aggregate<<<gAgg, 256, 0, stream>>>(x, bucket, start, deg, mean, n);
  int rpb = (n + 511) / 512;
  sage_gemm<0><<<512, 256, 0, stream>>>(mean, x, wt, wt + 16384, b1, x1, nullptr, n, rpb);
  k_aggregate<<<gAgg, 256, 0, stream>>>(x1, bucket, start, deg, mean, n);
  sage_gemm<1><<<512, 256, 0, stream>>>(mean, x1, wt + 32768, wt + 49152, b2, nullptr, out, n, rpb);
}

// Round 2
// 478.682 us; speedup vs baseline: 1.9893x; 1.9893x over previous
//
#include <hip/hip_runtime.h>

typedef unsigned short u16;
typedef unsigned int u32;
typedef short bf16x8 __attribute__((ext_vector_type(8)));
typedef float f32x4 __attribute__((ext_vector_type(4)));

static __device__ __forceinline__ float relu(float v) { return v > 0.f ? v : 0.f; }

static __device__ __forceinline__ u16 f2bf(float f) {
  u32 u = __float_as_uint(f);
  u32 r = (u + 0x7FFF + ((u >> 16) & 1)) >> 16;
  return (u16)r;
}
static __device__ __forceinline__ float bflo(u32 u) { return __uint_as_float(u << 16); }
static __device__ __forceinline__ float bfhi(u32 u) { return __uint_as_float(u & 0xFFFF0000u); }

// ---------------- weight prep: pack both layers' [Wl;Wr] into MFMA B-fragment order ----------------
// B[k][j], k in [0,256), j in [0,128). k<128 -> Wl[j][k], else Wr[j][k-128].
// Fragment order: [m(2)][ks(8)][jb(8)][lane(64)][e(8)], lane: j=jb*16+(l&15), k=ks*32+(l>>4)*8+e.
__global__ __launch_bounds__(256) void k_prep(
    const float* __restrict__ w1l, const float* __restrict__ w1r,
    const float* __restrict__ w2l, const float* __restrict__ w2r,
    u16* __restrict__ bfrag) {
  int i = blockIdx.x * 256 + threadIdx.x;  // 0..65535
  int e = i & 7;
  int lane = (i >> 3) & 63;
  int jb = (i >> 9) & 7;
  int ks = (i >> 12) & 7;
  int m = i >> 15;
  int k = ks * 32 + (lane >> 4) * 8 + e;
  int j = jb * 16 + (lane & 15);
  const float* wl = m ? w2l : w1l;
  const float* wr = m ? w2r : w1r;
  float v = (k < 128) ? wl[j * 128 + k] : wr[j * 128 + (k - 128)];
  bfrag[i] = f2bf(v);
}

// ---------------- f32 -> bf16 conversion (8 elems/thread) ----------------
__global__ __launch_bounds__(256) void k_f2b(const float* __restrict__ x,
                                             u16* __restrict__ xb, int total8) {
  int i = blockIdx.x * 256 + threadIdx.x;
  if (i >= total8) return;
  const float4* xp = (const float4*)x;
  float4 a = xp[i * 2];
  float4 b = xp[i * 2 + 1];
  uint4 o;
  o.x = (u32)f2bf(a.x) | ((u32)f2bf(a.y) << 16);
  o.y = (u32)f2bf(a.z) | ((u32)f2bf(a.w) << 16);
  o.z = (u32)f2bf(b.x) | ((u32)f2bf(b.y) << 16);
  o.w = (u32)f2bf(b.z) | ((u32)f2bf(b.w) << 16);
  ((uint4*)xb)[i] = o;
}

// ---------------- CSR build ----------------
__global__ __launch_bounds__(256) void k_degree(const int* __restrict__ dst,
                                                int* __restrict__ deg, int e) {
  int i = blockIdx.x * 256 + threadIdx.x;
  if (i < e) atomicAdd(&deg[dst[i]], 1);
}

__global__ __launch_bounds__(256) void k_scan(const int* __restrict__ deg,
                                              int* __restrict__ start,
                                              int* __restrict__ cursor,
                                              int* __restrict__ total, int n) {
  int gid = blockIdx.x * 256 + threadIdx.x;
  int lane = threadIdx.x & 63;
  int d = (gid < n) ? deg[gid] : 0;
  int incl = d;
#pragma unroll
  for (int off = 1; off < 64; off <<= 1) {
    int t = __shfl_up(incl, off, 64);
    if (lane >= off) incl += t;
  }
  int wsum = __shfl(incl, 63, 64);
  int base = 0;
  if (lane == 63) base = atomicAdd(total, wsum);
  base = __shfl(base, 63, 64);
  if (gid < n) {
    int st = base + incl - d;
    start[gid] = st;
    cursor[gid] = st;
  }
}

__global__ __launch_bounds__(256) void k_bucket(const int* __restrict__ src,
                                                const int* __restrict__ dst,
                                                int* __restrict__ cursor,
                                                int* __restrict__ bucket, int e) {
  int i = blockIdx.x * 256 + threadIdx.x;
  if (i < e) {
    int pos = atomicAdd(&cursor[dst[i]], 1);
    bucket[pos] = src[i];
  }
}

// ---------------- mean aggregation, bf16 in/out, f32 accum. one wave per node ----------------
__global__ __launch_bounds__(256) void k_agg(const u16* __restrict__ h,
                                             const int* __restrict__ bucket,
                                             const int* __restrict__ start,
                                             const int* __restrict__ deg,
                                             u16* __restrict__ mean, int n) {
  int node = blockIdx.x * 4 + (threadIdx.x >> 6);
  if (node >= n) return;
  int lane = threadIdx.x & 63;
  int s = start[node];
  int cnt = deg[node];
  float ax = 0.f, ay = 0.f;
  const u32* hp = (const u32*)h + lane;  // row stride = 64 u32
  int k = s, end = s + cnt;
  for (; k + 4 <= end; k += 4) {
    int i0 = bucket[k], i1 = bucket[k + 1], i2 = bucket[k + 2], i3 = bucket[k + 3];
    u32 u0 = hp[(size_t)i0 * 64];
    u32 u1 = hp[(size_t)i1 * 64];
    u32 u2 = hp[(size_t)i2 * 64];
    u32 u3 = hp[(size_t)i3 * 64];
    ax += bflo(u0) + bflo(u1) + bflo(u2) + bflo(u3);
    ay += bfhi(u0) + bfhi(u1) + bfhi(u2) + bfhi(u3);
  }
  for (; k < end; ++k) {
    u32 u = hp[(size_t)bucket[k] * 64];
    ax += bflo(u);
    ay += bfhi(u);
  }
  float inv = 1.f / (float)(cnt > 0 ? cnt : 1);
  ((u32*)mean)[(size_t)node * 64 + lane] =
      (u32)f2bf(ax * inv) | ((u32)f2bf(ay * inv) << 16);
}

// ---------------- fused SAGE layer GEMM: out[r][h] = relu(bias[h] + [mean|xin] @ Bfrag) ----------------
// MODE 0: write x1b (bf16 [n,128]) and out-plane0 (f32, stride 2).
// MODE 1: write out-plane1 (f32, stride 2).
template <int MODE>
__global__ __launch_bounds__(256) void sage_mfma(
    const u16* __restrict__ Amean, const u16* __restrict__ Ax,
    const u16* __restrict__ Bfrag, const float* __restrict__ bias,
    u16* __restrict__ x1out, float* __restrict__ out, int n) {
  __shared__ u16 lA[128 * 256];  // 64 KB, row-major K=256, XOR chunk swizzle
  __shared__ u16 lB[32768];      // 64 KB, fragment order

  int tid = threadIdx.x;
  int lane = tid & 63;
  int wid = tid >> 6;
  int l15 = lane & 15, lhi = lane >> 4;
  int wr = wid >> 1, wc = wid & 1;
  int r0 = blockIdx.x * 128;

  // stage B (linear 64 KB)
  {
    const uint4* bsrc = (const uint4*)Bfrag;
    uint4* bdst = (uint4*)lB;
#pragma unroll
    for (int i = 0; i < 16; ++i) bdst[tid + i * 256] = bsrc[tid + i * 256];
  }
  // stage A (swizzled row-major). 128 rows x 512 B; chunk = 16 B.
  {
#pragma unroll
    for (int it = 0; it < 16; ++it) {
      int i = tid + it * 256;
      int row = i >> 5;
      int c = i & 31;
      int gr = r0 + row;
      uint4 v = {0u, 0u, 0u, 0u};
      if (gr < n) {
        const u16* srcp = (c < 16) ? (Amean + (size_t)gr * 128 + c * 8)
                                   : (Ax + (size_t)gr * 128 + (c - 16) * 8);
        v = *(const uint4*)srcp;
      }
      int byteoff = (row * 512 + c * 16) ^ ((row & 7) << 4);
      *(uint4*)((char*)lA + byteoff) = v;
    }
  }

  float bs[4];
#pragma unroll
  for (int nj = 0; nj < 4; ++nj) bs[nj] = bias[wc * 64 + nj * 16 + l15];

  __syncthreads();

  f32x4 acc[4][4];
#pragma unroll
  for (int mi = 0; mi < 4; ++mi)
#pragma unroll
    for (int nj = 0; nj < 4; ++nj) acc[mi][nj] = (f32x4){0.f, 0.f, 0.f, 0.f};

#pragma unroll
  for (int ks = 0; ks < 8; ++ks) {
    bf16x8 af[4], bfr[4];
#pragma unroll
    for (int mi = 0; mi < 4; ++mi) {
      int row = wr * 64 + mi * 16 + l15;
      int byteoff = (row * 512 + ks * 64 + lhi * 16) ^ ((row & 7) << 4);
      af[mi] = *(const bf16x8*)((const char*)lA + byteoff);
    }
#pragma unroll
    for (int nj = 0; nj < 4; ++nj) {
      int jb = wc * 4 + nj;
      bfr[nj] = *(const bf16x8*)((const char*)lB + ((ks * 8 + jb) * 64 + lane) * 16);
    }
#pragma unroll
    for (int mi = 0; mi < 4; ++mi)
#pragma unroll
      for (int nj = 0; nj < 4; ++nj)
        acc[mi][nj] = __builtin_amdgcn_mfma_f32_16x16x32_bf16(af[mi], bfr[nj],
                                                              acc[mi][nj], 0, 0, 0);
  }

  // epilogue
#pragma unroll
  for (int mi = 0; mi < 4; ++mi) {
#pragma unroll
    for (int r = 0; r < 4; ++r) {
      int rowt = wr * 64 + mi * 16 + lhi * 4 + r;
      int row = r0 + rowt;
      if (row < n) {
#pragma unroll
        for (int nj = 0; nj < 4; ++nj) {
          int col = wc * 64 + nj * 16 + l15;
          float v = relu(acc[mi][nj][r] + bs[nj]);
          if (MODE == 0) {
            x1out[(size_t)row * 128 + col] = f2bf(v);
            out[((size_t)row * 128 + col) * 2] = v;       // plane 0 = x1 (f32 exact)
          } else {
            out[((size_t)row * 128 + col) * 2 + 1] = v;   // plane 1 = x2
          }
        }
      }
    }
  }
}

extern "C" void kernel_launch(void* const* d_in, const int* in_sizes, int n_in,
                              void* d_out, int out_size, void* d_ws, size_t ws_size,
                              hipStream_t stream) {
  const float* x = (const float*)d_in[0];
  const int* ei = (const int*)d_in[1];
  const float* w1l = (const float*)d_in[2];
  const float* b1 = (const float*)d_in[3];
  const float* w1r = (const float*)d_in[4];
  const float* w2l = (const float*)d_in[5];
  const float* b2 = (const float*)d_in[6];
  const float* w2r = (const float*)d_in[7];
  float* out = (float*)d_out;

  int n = in_sizes[0] / 128;
  int e = in_sizes[1] / 2;
  const int* src = ei;
  const int* dst = ei + e;

  char* ws = (char*)d_ws;
  size_t off = 0;
  auto alloc = [&](size_t bytes) {
    void* p = ws + off;
    off += (bytes + 255) & ~(size_t)255;
    return p;
  };
  u16* bfrag = (u16*)alloc(65536 * sizeof(u16));
  int* deg = (int*)alloc((size_t)n * 4);
  int* start = (int*)alloc((size_t)n * 4);
  int* cursor = (int*)alloc((size_t)n * 4);
  int* total = (int*)alloc(256);
  int* bucket = (int*)alloc((size_t)e * 4);
  u16* xb = (u16*)alloc((size_t)n * 128 * sizeof(u16));
  u16* meanb = (u16*)alloc((size_t)n * 128 * sizeof(u16));
  u16* x1b = (u16*)alloc((size_t)n * 128 * sizeof(u16));
  (void)ws_size;
  (void)n_in;
  (void)out_size;

  hipMemsetAsync(deg, 0, (size_t)n * 4, stream);
  hipMemsetAsync(total, 0, 4, stream);

  k_prep<<<256, 256, 0, stream>>>(w1l, w1r, w2l, w2r, bfrag);
  k_f2b<<<(n * 128 / 8 + 255) / 256, 256, 0, stream>>>(x, xb, n * 128 / 8);

  int gE = (e + 255) / 256;
  k_degree<<<gE, 256, 0, stream>>>(dst, deg, e);
  int gN = (n + 255) / 256;
  k_scan<<<gN, 256, 0, stream>>>(deg, start, cursor, total, n);
  k_bucket<<<gE, 256, 0, stream>>>(src, dst, cursor, bucket, e);

  int gAgg = (n + 3) / 4;
  int gGemm = (n + 127) / 128;
  k_agg<<<gAgg, 256, 0, stream>>>(xb, bucket, start, deg, meanb, n);
  sage_mfma<0><<<gGemm, 256, 0, stream>>>(meanb, xb, bfrag, b1, x1b, out, n);
  k_agg<<<gAgg, 256, 0, stream>>>(x1b, bucket, start, deg, meanb, n);
  sage_mfma<1><<<gGemm, 256, 0, stream>>>(meanb, x1b, bfrag + 32768, b2, nullptr, out, n);
}